// Round 2
// 3883.463 us; speedup vs baseline: 1.1831x; 1.1831x over previous
//
#include <hip/hip_runtime.h>
#include <stdint.h>

typedef unsigned short u16;
typedef __attribute__((ext_vector_type(8))) short short8;
typedef __attribute__((ext_vector_type(4))) float f32x4;

#define T_SEQ 1024
#define HDIM  1024
#define NG    3072
#define SLOT  16384          // elements per time-slot: 64 strips * 256
#define FSTRIDE 32           // u32 stride between flags (128 B, own line)

__device__ __forceinline__ u16 f2bf(float f) {
  unsigned u = __float_as_uint(f);
  u += 0x7FFF + ((u >> 16) & 1);
  return (u16)(u >> 16);
}
__device__ __forceinline__ float bf2f(u16 h) {
  return __uint_as_float(((unsigned)h) << 16);
}

// async global->LDS, 16B per lane (GEMM staging only). LDS dest = uniform base + lane*16.
__device__ __forceinline__ void gld16(void* lds, const void* g) {
  __builtin_amdgcn_global_load_lds(
      (const __attribute__((address_space(1))) unsigned*)g,
      (__attribute__((address_space(3))) unsigned*)lds, 16, 0, 0);
}

__device__ __forceinline__ void st_agent_u32(unsigned* p, unsigned v) {
  __hip_atomic_store(p, v, __ATOMIC_RELAXED, __HIP_MEMORY_SCOPE_AGENT);
}
__device__ __forceinline__ unsigned ld_agent_u32(const unsigned* p) {
  return __hip_atomic_load(p, __ATOMIC_RELAXED, __HIP_MEMORY_SCOPE_AGENT);
}

// wave-level: wait until flags[16*wave + 0..15] >= need. 16 producers per wave
// (the producers of this wave's K-slice). Compiler barrier keeps data loads after.
__device__ __forceinline__ void poll16(const unsigned* flags, int wave, int lane, unsigned need) {
  if (lane < 16) {
    const unsigned* f = flags + (size_t)(16 * wave + lane) * FSTRIDE;
    while (ld_agent_u32(f) < need) {}
  }
  asm volatile("" ::: "memory");
}

// ---------------- prep: cast 5 weight tensors fp32->bf16, zero barrier flags ----
__global__ void cast5_kernel(const float* __restrict__ s0, const float* __restrict__ s1,
                             const float* __restrict__ s2, const float* __restrict__ s3,
                             const float* __restrict__ s4,
                             u16* __restrict__ d0, u16* __restrict__ d1,
                             u16* __restrict__ d2, u16* __restrict__ d3,
                             u16* __restrict__ d4, unsigned* __restrict__ flags) {
  if (blockIdx.x == 0) {
#pragma unroll
    for (int k = 0; k < 32; ++k) flags[threadIdx.x * 32 + k] = 0;  // 32 KB of flags
  }
  int bid = blockIdx.x;
  const float* s; u16* d; size_t base;
  if (bid < 3072)       { s = s0; d = d0; base = (size_t)bid * 1024; }
  else if (bid < 6144)  { s = s1; d = d1; base = (size_t)(bid - 3072) * 1024; }
  else if (bid < 9216)  { s = s2; d = d2; base = (size_t)(bid - 6144) * 1024; }
  else if (bid < 12288) { s = s3; d = d3; base = (size_t)(bid - 9216) * 1024; }
  else                  { s = s4; d = d4; base = (size_t)(bid - 12288) * 1024; }
  size_t i = base + (size_t)threadIdx.x * 4;
  float4 v = *(const float4*)(s + i);
  unsigned lo = (unsigned)f2bf(v.x) | ((unsigned)f2bf(v.y) << 16);
  unsigned hi = (unsigned)f2bf(v.z) | ((unsigned)f2bf(v.w) << 16);
  uint2 o; o.x = lo; o.y = hi;
  *(uint2*)(d + i) = o;
}

// ---------------- embedding gather + cast to bf16 ------------------------------
__global__ void gather_cast_kernel(const int* __restrict__ tokens,
                                   const float* __restrict__ emb,
                                   u16* __restrict__ xbf) {
  int row = blockIdx.x;                 // 0..16383  (= b*T + t)
  int tok = tokens[row];
  const float4* src = (const float4*)(emb + (size_t)tok * HDIM);
  float4 v = src[threadIdx.x];
  unsigned lo = (unsigned)f2bf(v.x) | ((unsigned)f2bf(v.y) << 16);
  unsigned hi = (unsigned)f2bf(v.z) | ((unsigned)f2bf(v.w) << 16);
  uint2 o; o.x = lo; o.y = hi;
  *(uint2*)(xbf + (size_t)row * HDIM + (size_t)threadIdx.x * 4) = o;
}

// ---------------- bf16 MFMA GEMM, C[m,n] = sum_k A[m,k]*Bt[n,k] -----------------
// A_PACKED: A is the packed scan layout h[t][prod][b][16]; logical row r = b*T+t
// maps to slot t+1 (state after step t).
template <bool OUT_BF16, bool A_PACKED, bool ADD_BIAS>
__global__ __launch_bounds__(256)
void gemm_bt(const u16* __restrict__ A, const u16* __restrict__ Bt,
             void* __restrict__ Cout, const float* __restrict__ bias,
             int M, int N) {
  const int K = 1024;
  __shared__ u16 As[128 * 32];
  __shared__ u16 Bs[128 * 32];
  const int tid = threadIdx.x;
  const int wave = tid >> 6, lane = tid & 63;
  const int quad = lane >> 4, l16 = lane & 15;
  const int wm = (wave & 1) * 64, wn = (wave >> 1) * 64;
  const int m0 = blockIdx.x * 128, n0 = blockIdx.y * 128;
  const int srow = tid >> 2, scol = (tid & 3) * 8;

  size_t abase0, abase1;
  {
    int r0 = m0 + srow, r1 = m0 + 64 + srow;
    if (A_PACKED) {
      abase0 = (size_t)((r0 & 1023) + 1) * SLOT + (size_t)(r0 >> 10) * 16 +
               (size_t)(scol & 8) + (size_t)(scol >> 4) * 256;
      abase1 = (size_t)((r1 & 1023) + 1) * SLOT + (size_t)(r1 >> 10) * 16 +
               (size_t)(scol & 8) + (size_t)(scol >> 4) * 256;
    } else {
      abase0 = (size_t)r0 * K + scol;
      abase1 = (size_t)r1 * K + scol;
    }
  }
  const size_t bbase0 = (size_t)(n0 + srow) * K + scol;
  const size_t bbase1 = (size_t)(n0 + 64 + srow) * K + scol;

  f32x4 acc[4][4] = {};

  for (int kk = 0; kk < K; kk += 32) {
    __syncthreads();
    size_t ka = A_PACKED ? (size_t)kk * 16 : (size_t)kk;   // 32 cols = 2 strips = 512 elems
    gld16(&As[srow * 32 + scol],        A + abase0 + ka);
    gld16(&As[(64 + srow) * 32 + scol], A + abase1 + ka);
    gld16(&Bs[srow * 32 + scol],        Bt + bbase0 + kk);
    gld16(&Bs[(64 + srow) * 32 + scol], Bt + bbase1 + kk);
    __syncthreads();
    short8 af[4], bfr[4];
#pragma unroll
    for (int mt = 0; mt < 4; ++mt)
      af[mt] = *(const short8*)&As[(wm + mt * 16 + l16) * 32 + quad * 8];
#pragma unroll
    for (int nt = 0; nt < 4; ++nt)
      bfr[nt] = *(const short8*)&Bs[(wn + nt * 16 + l16) * 32 + quad * 8];
#pragma unroll
    for (int mt = 0; mt < 4; ++mt)
#pragma unroll
      for (int nt = 0; nt < 4; ++nt)
        acc[mt][nt] = __builtin_amdgcn_mfma_f32_16x16x32_bf16(af[mt], bfr[nt], acc[mt][nt], 0, 0, 0);
  }
#pragma unroll
  for (int mt = 0; mt < 4; ++mt) {
#pragma unroll
    for (int nt = 0; nt < 4; ++nt) {
#pragma unroll
      for (int r = 0; r < 4; ++r) {
        int m = m0 + wm + mt * 16 + quad * 4 + r;
        int n = n0 + wn + nt * 16 + l16;
        float v = acc[mt][nt][r];
        if (ADD_BIAS) v += bias[n];
        if (OUT_BF16) ((u16*)Cout)[(size_t)m * N + n] = f2bf(v);
        else          ((float*)Cout)[(size_t)m * N + n] = v;
      }
    }
  }
}

// ---------------- fused 2-layer persistent GRU scan, 128 WGs --------------------
// h layout: h[t][producer wg 0..63][batch 0..15][16 cols] bf16; each producer's
// step output is one contiguous 512 B strip. Consumers load MFMA fragments
// DIRECTLY to registers (no LDS staging): wave w's K-slice = producers 16w..16w+15,
// polled per-wave. Layer 1 prefetches h1 fragments one step ahead and runs its
// x-matvec in the shadow of the h2 handoff.
__global__ __launch_bounds__(256, 1)
void fused_scan_kernel(const u16* __restrict__ gx0,
                       u16* __restrict__ h1p, u16* __restrict__ h2p,
                       const u16* __restrict__ Whh0, const u16* __restrict__ Wih1,
                       const u16* __restrict__ Whh1,
                       const float* __restrict__ bih0, const float* __restrict__ bhh0,
                       const float* __restrict__ bih1, const float* __restrict__ bhh1,
                       unsigned* __restrict__ flags0, unsigned* __restrict__ flags1) {
  const int tid = threadIdx.x;
  const int wave = tid >> 6, lane = tid & 63;
  const int quad = lane >> 4, l16 = lane & 15;
  const int eb = tid >> 4, ej = tid & 15;

  __shared__ float part[4][6][256];
  __shared__ float biasS[2][3][16];

  // fragment source offset within a slot: prod = 16w + 2s + (quad>>1),
  // elem = prod*256 + batch(l16)*16 + (quad&1)*8 ; + s*512 per k-subtile
  const int fragoff = (16 * wave + (quad >> 1)) * 256 + l16 * 16 + (quad & 1) * 8;

  if (blockIdx.x < 64) {
    // ======================= LAYER 0 =======================
    const int wg = blockIdx.x, j0 = wg * 16;
    short8 wf[3][8];
#pragma unroll
    for (int g = 0; g < 3; ++g)
#pragma unroll
      for (int s = 0; s < 8; ++s)
        wf[g][s] = *(const short8*)&Whh0[(size_t)(g * 1024 + j0 + l16) * 1024 + wave * 256 + s * 32 + quad * 8];
    if (tid < 96) {
      int a = tid / 48, rem = tid % 48, g = rem >> 4, jl = rem & 15;
      biasS[a][g][jl] = (a ? bhh0 : bih0)[g * 1024 + j0 + jl];
    }
    if (tid < 128) st_agent_u32((unsigned*)h1p + wg * 128 + tid, 0u);  // zero own strip, slot 0
    __syncthreads();
    if (tid == 0)
      __hip_atomic_store(flags0 + (size_t)wg * FSTRIDE, 1u, __ATOMIC_RELEASE, __HIP_MEMORY_SCOPE_AGENT);

    const u16* gxp = gx0 + (size_t)eb * T_SEQ * NG + j0 + ej;
    u16 gxu0 = gxp[0], gxu1 = gxp[1024], gxu2 = gxp[2048];
    float hprev = 0.f;

    for (int t = 0; t < T_SEQ; ++t) {
      poll16(flags0, wave, lane, (unsigned)(t + 1));
      // issue next step's gx prefetch first: independent loads, overlap the matvec
      int tn = (t + 1 < T_SEQ) ? t + 1 : t;
      const u16* gpn = gx0 + ((size_t)eb * T_SEQ + tn) * NG + j0 + ej;
      u16 ng0 = gpn[0], ng1 = gpn[1024], ng2 = gpn[2048];
      const u16* src = h1p + (size_t)t * SLOT + fragoff;
      short8 af[8];
#pragma unroll
      for (int s = 0; s < 8; ++s) af[s] = *(const short8*)(src + s * 512);
      f32x4 a0 = {0.f,0.f,0.f,0.f}, a1 = {0.f,0.f,0.f,0.f}, a2 = {0.f,0.f,0.f,0.f};
#pragma unroll
      for (int s = 0; s < 8; ++s) {
        a0 = __builtin_amdgcn_mfma_f32_16x16x32_bf16(af[s], wf[0][s], a0, 0, 0, 0);
        a1 = __builtin_amdgcn_mfma_f32_16x16x32_bf16(af[s], wf[1][s], a1, 0, 0, 0);
        a2 = __builtin_amdgcn_mfma_f32_16x16x32_bf16(af[s], wf[2][s], a2, 0, 0, 0);
      }
#pragma unroll
      for (int r = 0; r < 4; ++r) {
        int o = (quad * 4 + r) * 16 + l16;
        part[wave][0][o] = a0[r]; part[wave][1][o] = a1[r]; part[wave][2][o] = a2[r];
      }
      __syncthreads();
      float ghr = part[0][0][tid] + part[1][0][tid] + part[2][0][tid] + part[3][0][tid] + biasS[1][0][ej];
      float ghz = part[0][1][tid] + part[1][1][tid] + part[2][1][tid] + part[3][1][tid] + biasS[1][1][ej];
      float ghn = part[0][2][tid] + part[1][2][tid] + part[2][2][tid] + part[3][2][tid] + biasS[1][2][ej];
      float xr = bf2f(gxu0) + biasS[0][0][ej] + ghr;
      float xz = bf2f(gxu1) + biasS[0][1][ej] + ghz;
      float xn = bf2f(gxu2) + biasS[0][2][ej];
      float r_ = 1.f / (1.f + __expf(-xr));
      float z_ = 1.f / (1.f + __expf(-xz));
      float pre = fminf(fmaxf(xn + r_ * ghn, -15.f), 15.f);
      float e2 = __expf(2.f * pre);
      float n_ = (e2 - 1.f) / (e2 + 1.f);
      float hn = (1.f - z_) * n_ + z_ * hprev;
      hprev = hn;
      gxu0 = ng0; gxu1 = ng1; gxu2 = ng2;

      unsigned mine = (unsigned)f2bf(hn);
      unsigned other = __shfl_xor(mine, 1);
      if (!(tid & 1))
        st_agent_u32((unsigned*)h1p + (size_t)(t + 1) * (SLOT / 2) + wg * 128 + (tid >> 1),
                     mine | (other << 16));
      __syncthreads();  // drain strip stores (+ protects part[] reuse)
      if (tid == 0)
        __hip_atomic_store(flags0 + (size_t)wg * FSTRIDE, (unsigned)(t + 2), __ATOMIC_RELEASE, __HIP_MEMORY_SCOPE_AGENT);
    }
  } else {
    // ======================= LAYER 1 =======================
    const int wg = blockIdx.x - 64, j0 = wg * 16;
    short8 wfX[3][8], wfH[3][8];
#pragma unroll
    for (int g = 0; g < 3; ++g)
#pragma unroll
      for (int s = 0; s < 8; ++s) {
        size_t row = (size_t)(g * 1024 + j0 + l16) * 1024 + wave * 256 + s * 32 + quad * 8;
        wfX[g][s] = *(const short8*)&Wih1[row];
        wfH[g][s] = *(const short8*)&Whh1[row];
      }
    if (tid < 96) {
      int a = tid / 48, rem = tid % 48, g = rem >> 4, jl = rem & 15;
      biasS[a][g][jl] = (a ? bhh1 : bih1)[g * 1024 + j0 + jl];
    }
    if (tid < 128) st_agent_u32((unsigned*)h2p + wg * 128 + tid, 0u);  // zero own strip, slot 0
    __syncthreads();
    if (tid == 0)
      __hip_atomic_store(flags1 + (size_t)wg * FSTRIDE, 1u, __ATOMIC_RELEASE, __HIP_MEMORY_SCOPE_AGENT);

    // preload h1 fragments for t=0 (h1 slot 1: layer-0 step 0 output)
    short8 af1[8];
    poll16(flags0, wave, lane, 2u);
    {
      const u16* s1 = h1p + (size_t)SLOT + fragoff;
#pragma unroll
      for (int s = 0; s < 8; ++s) af1[s] = *(const short8*)(s1 + s * 512);
    }
    float hprev = 0.f;

    for (int t = 0; t < T_SEQ; ++t) {
      // x-matvec on preloaded af1 — runs in the shadow of other WGs' h2 handoff
      f32x4 x0 = {0.f,0.f,0.f,0.f}, x1 = {0.f,0.f,0.f,0.f}, x2 = {0.f,0.f,0.f,0.f};
#pragma unroll
      for (int s = 0; s < 8; ++s) {
        x0 = __builtin_amdgcn_mfma_f32_16x16x32_bf16(af1[s], wfX[0][s], x0, 0, 0, 0);
        x1 = __builtin_amdgcn_mfma_f32_16x16x32_bf16(af1[s], wfX[1][s], x1, 0, 0, 0);
        x2 = __builtin_amdgcn_mfma_f32_16x16x32_bf16(af1[s], wfX[2][s], x2, 0, 0, 0);
      }
      // h2[t] handoff: poll own-layer producers, fragments direct to registers
      poll16(flags1, wave, lane, (unsigned)(t + 1));
      short8 af2[8];
      const u16* s2 = h2p + (size_t)t * SLOT + fragoff;
#pragma unroll
      for (int s = 0; s < 8; ++s) af2[s] = *(const short8*)(s2 + s * 512);
      // prefetch next step's h1 fragments (slot t+2); layer 0 runs ahead
      if (t + 1 < T_SEQ) {
        poll16(flags0, wave, lane, (unsigned)(t + 3));
        const u16* s1 = h1p + (size_t)(t + 2) * SLOT + fragoff;
#pragma unroll
        for (int s = 0; s < 8; ++s) af1[s] = *(const short8*)(s1 + s * 512);
      }
      f32x4 h0 = {0.f,0.f,0.f,0.f}, h1a = {0.f,0.f,0.f,0.f}, h2a = {0.f,0.f,0.f,0.f};
#pragma unroll
      for (int s = 0; s < 8; ++s) {
        h0  = __builtin_amdgcn_mfma_f32_16x16x32_bf16(af2[s], wfH[0][s], h0, 0, 0, 0);
        h1a = __builtin_amdgcn_mfma_f32_16x16x32_bf16(af2[s], wfH[1][s], h1a, 0, 0, 0);
        h2a = __builtin_amdgcn_mfma_f32_16x16x32_bf16(af2[s], wfH[2][s], h2a, 0, 0, 0);
      }
#pragma unroll
      for (int r = 0; r < 4; ++r) {
        int o = (quad * 4 + r) * 16 + l16;
        part[wave][0][o] = x0[r];  part[wave][1][o] = x1[r];  part[wave][2][o] = x2[r];
        part[wave][3][o] = h0[r];  part[wave][4][o] = h1a[r]; part[wave][5][o] = h2a[r];
      }
      __syncthreads();
      float sxr = part[0][0][tid] + part[1][0][tid] + part[2][0][tid] + part[3][0][tid] + biasS[0][0][ej];
      float sxz = part[0][1][tid] + part[1][1][tid] + part[2][1][tid] + part[3][1][tid] + biasS[0][1][ej];
      float sxn = part[0][2][tid] + part[1][2][tid] + part[2][2][tid] + part[3][2][tid] + biasS[0][2][ej];
      float shr = part[0][3][tid] + part[1][3][tid] + part[2][3][tid] + part[3][3][tid] + biasS[1][0][ej];
      float shz = part[0][4][tid] + part[1][4][tid] + part[2][4][tid] + part[3][4][tid] + biasS[1][1][ej];
      float shn = part[0][5][tid] + part[1][5][tid] + part[2][5][tid] + part[3][5][tid] + biasS[1][2][ej];
      float r_ = 1.f / (1.f + __expf(-(sxr + shr)));
      float z_ = 1.f / (1.f + __expf(-(sxz + shz)));
      float pre = fminf(fmaxf(sxn + r_ * shn, -15.f), 15.f);
      float e2 = __expf(2.f * pre);
      float n_ = (e2 - 1.f) / (e2 + 1.f);
      float hn = (1.f - z_) * n_ + z_ * hprev;
      hprev = hn;

      unsigned mine = (unsigned)f2bf(hn);
      unsigned other = __shfl_xor(mine, 1);
      if (!(tid & 1))
        st_agent_u32((unsigned*)h2p + (size_t)(t + 1) * (SLOT / 2) + wg * 128 + (tid >> 1),
                     mine | (other << 16));
      __syncthreads();  // drain strip stores (+ protects part[] reuse)
      if (tid == 0)
        __hip_atomic_store(flags1 + (size_t)wg * FSTRIDE, (unsigned)(t + 2), __ATOMIC_RELEASE, __HIP_MEMORY_SCOPE_AGENT);
    }
  }
}

// ---------------- log_softmax over axis=1 (T): grid (16 b, 8 cgroups) ----------
__global__ void logsoftmax_kernel(float* __restrict__ out) {
  int b = blockIdx.x, cg = blockIdx.y;
  int ci = threadIdx.x & 15, ts = threadIdx.x >> 4;   // 16 cols x 16 t-strips
  int c = cg * 16 + ci;
  float m = -1e30f, s = 0.f;
  for (int t = ts; t < T_SEQ; t += 16) {
    float v = out[((size_t)b * T_SEQ + t) * 128 + c];
    if (v > m) { s = s * __expf(m - v) + 1.f; m = v; }
    else s += __expf(v - m);
  }
  __shared__ float mS[16][16], sS[16][16];
  mS[ts][ci] = m; sS[ts][ci] = s;
  __syncthreads();
  if (ts == 0) {
    float M = mS[0][ci], S = sS[0][ci];
#pragma unroll
    for (int k = 1; k < 16; ++k) {
      float m2 = mS[k][ci], s2 = sS[k][ci];
      float nm = fmaxf(M, m2);
      S = S * __expf(M - nm) + s2 * __expf(m2 - nm);
      M = nm;
    }
    sS[0][ci] = M + logf(S);
  }
  __syncthreads();
  float lsd = sS[0][ci];
  for (int t = ts; t < T_SEQ; t += 16) {
    size_t i = ((size_t)b * T_SEQ + t) * 128 + c;
    out[i] -= lsd;
  }
}

// --------------------------------------------------------------------------------
extern "C" void kernel_launch(void* const* d_in, const int* in_sizes, int n_in,
                              void* d_out, int out_size, void* d_ws, size_t ws_size,
                              hipStream_t stream) {
  const int*   tokens = (const int*)d_in[0];
  const float* emb  = (const float*)d_in[1];
  const float* Wih0 = (const float*)d_in[2];
  const float* Whh0 = (const float*)d_in[3];
  const float* bih0 = (const float*)d_in[4];
  const float* bhh0 = (const float*)d_in[5];
  const float* Wih1 = (const float*)d_in[6];
  const float* Whh1 = (const float*)d_in[7];
  const float* bih1 = (const float*)d_in[8];
  const float* bhh1 = (const float*)d_in[9];
  const float* Wlin = (const float*)d_in[10];
  const float* blin = (const float*)d_in[11];
  float* out = (float*)d_out;

  uint8_t* ws = (uint8_t*)d_ws;
  size_t off = 0;
  auto alloc = [&](size_t bytes) -> void* {
    void* p = ws + off;
    off += (bytes + 255) & ~(size_t)255;
    return p;
  };
  u16* h1p   = (u16*)alloc((size_t)(T_SEQ + 1) * SLOT * 2);  // packed h1 slots
  u16* h2p   = (u16*)alloc((size_t)(T_SEQ + 1) * SLOT * 2);  // packed h2 slots
  u16* xbf   = h2p;   // x_bf aliases h2p: fully consumed by gx0 GEMM before the scan
  u16* gxbuf = (u16*)alloc((size_t)16384 * NG * 2);          // layer-0 input gates
  u16* wih0b = (u16*)alloc((size_t)NG * HDIM * 2);
  u16* whh0b = (u16*)alloc((size_t)NG * HDIM * 2);
  u16* wih1b = (u16*)alloc((size_t)NG * HDIM * 2);
  u16* whh1b = (u16*)alloc((size_t)NG * HDIM * 2);
  u16* wlinb = (u16*)alloc((size_t)128 * HDIM * 2);
  unsigned* flags = (unsigned*)alloc(32768);   // flags0 = [0..2047], flags1 = [2048..4095]

  cast5_kernel<<<dim3(12416), dim3(256), 0, stream>>>(
      Wih0, Whh0, Wih1, Whh1, Wlin, wih0b, whh0b, wih1b, whh1b, wlinb, flags);
  gather_cast_kernel<<<dim3(16384), dim3(256), 0, stream>>>(tokens, emb, xbf);
  // gx0 = x @ W_ih0^T
  gemm_bt<true, false, false><<<dim3(128, 24), dim3(256), 0, stream>>>(
      xbf, wih0b, gxbuf, nullptr, 16384, NG);
  // fused 2-layer scan (packed strips, register-direct fragments, per-wave polls)
  fused_scan_kernel<<<dim3(128), dim3(256), 0, stream>>>(
      gxbuf, h1p, h2p, whh0b, wih1b, whh1b, bih0, bhh0, bih1, bhh1,
      flags, flags + 64 * FSTRIDE);
  // logits = h2 @ W_lin^T + b_lin -> d_out (fp32); A read from packed h2 slots
  gemm_bt<false, true, true><<<dim3(128, 1), dim3(256), 0, stream>>>(
      h2p, wlinb, out, blin, 16384, 128);
  // log_softmax over T, in place
  logsoftmax_kernel<<<dim3(16, 8), dim3(256), 0, stream>>>(out);
}